// Round 6
// baseline (761.896 us; speedup 1.0000x reference)
//
#include <hip/hip_runtime.h>
#include <hip/hip_bf16.h>
#include <math.h>
#include <stdint.h>

// ---------- constants ----------
#define C_ 384
#define TOKENS 50176          // B*H*W = 16*56*56 = 16*64*49

typedef __bf16 bf16;
typedef __bf16 bf16x8 __attribute__((ext_vector_type(8)));
typedef __bf16 bf16x4 __attribute__((ext_vector_type(4)));
typedef float  f32x4  __attribute__((ext_vector_type(4)));

__device__ __forceinline__ float b2f(bf16 x) { return (float)x; }
__device__ __forceinline__ bf16  f2b(float x) { return (bf16)x; }

// tanh-form GELU: v * sigmoid(1.5957691 v + 0.0713548 v^3)
__device__ __forceinline__ float fast_gelu(float v) {
    float u2 = v * fmaf(v * v, 0.07135481f, 1.5957691f);
    return v / (1.0f + __expf(-u2));
}

// async global->LDS, 16 bytes per lane. LDS dest must be wave-uniform base + lane*16.
__device__ __forceinline__ void gld_lds16(const bf16* g, bf16* l) {
    __builtin_amdgcn_global_load_lds(
        (const __attribute__((address_space(1))) void*)g,
        (__attribute__((address_space(3))) void*)l, 16, 0, 0);
}

#define SYNC_FENCE() do { __builtin_amdgcn_sched_barrier(0); \
                          __builtin_amdgcn_s_barrier(); \
                          __builtin_amdgcn_sched_barrier(0); } while (0)

// ---------- K0: weight convert+transpose: in f32 [K][N] -> out bf16 [N][K] ----------
__global__ void wtrans_kernel(const float* __restrict__ in, bf16* __restrict__ out,
                              int K, int N) {
    int idx = blockIdx.x * 256 + threadIdx.x;
    if (idx >= K * N) return;
    int n = idx / K, k = idx % K;
    out[idx] = f2b(in[(size_t)k * N + n]);
}

// ---------- K1: LN1 + roll(-3,-3) + window partition. x BCHW f32 -> xw [50176][384] bf16 ----------
__global__ __launch_bounds__(256) void ln1_gather_kernel(
    const float* __restrict__ x, const float* __restrict__ g,
    const float* __restrict__ bt, bf16* __restrict__ xw) {
    int wave = threadIdx.x >> 6, lane = threadIdx.x & 63;
    int T = blockIdx.x * 4 + wave;
    int wi = T / 49, n = T % 49;
    int b = wi >> 6, w64 = wi & 63;
    int bh = w64 >> 3, bw = w64 & 7;
    int hs = bh * 7 + n / 7 + 3; if (hs >= 56) hs -= 56;
    int wsd = bw * 7 + n % 7 + 3; if (wsd >= 56) wsd -= 56;
    const float* xp = x + (size_t)b * C_ * 3136 + hs * 56 + wsd;
    float v[6];
    #pragma unroll
    for (int k = 0; k < 6; k++) v[k] = xp[(size_t)(lane + k * 64) * 3136];
    float s = v[0] + v[1] + v[2] + v[3] + v[4] + v[5];
    #pragma unroll
    for (int m = 32; m; m >>= 1) s += __shfl_xor(s, m);
    float mu = s * (1.0f / 384.0f);
    float s2 = 0.f;
    #pragma unroll
    for (int k = 0; k < 6; k++) { float d = v[k] - mu; s2 += d * d; }
    #pragma unroll
    for (int m = 32; m; m >>= 1) s2 += __shfl_xor(s2, m);
    float rstd = rsqrtf(s2 * (1.0f / 384.0f) + 1e-5f);
    bf16* op = xw + (size_t)T * 384;
    #pragma unroll
    for (int k = 0; k < 6; k++) {
        int c = lane + k * 64;
        op[c] = f2b((v[k] - mu) * rstd * g[c] + bt[c]);
    }
}

enum { EPI_NONE = 0, EPI_GELU = 1, EPI_PROJ = 2, EPI_FC2 = 3 };

// =============== streaming GEMM, m201-geometry ===============
// C[M][N] = A[M][K] @ Wt[N][K]^T + bias. BM=512, BN=128, BK=64, 512 threads =
// 8 waves as 4M x 2N -> wave tile 128x64 (acc 8x4): 24 KB LDS-read per 64 MFMA
// per wave (vs 512 B/MFMA of the old 64x64 tile). LDS = A dbuf 2x64K + B dbuf
// 2x16K = 160 KiB exactly, 1 block/CU. K-step: stage tile t+2 (counted
// vmcnt(10), never drains mid-loop), then 4 sub-batches interleaving
// {ds_read batch b+1 || 16 MFMA of batch b} gated by counted lgkmcnt
// (+sched_barrier(0), rule 18). Swizzle: LDS granule g of row r holds global
// granule g^(r&7); reads XOR back (verified 0-conflict; 2-way only).
// Grid n-inner + XCD-chunked bijective remap: consecutive blocks share the
// 512-row A panel on the same XCD L2.

__device__ __forceinline__ void stage_tile(const bf16* const (&gA)[8], const bf16* const (&gB)[2],
                                           bf16* Asb, bf16* Bsb, int t, int k0) {
    #pragma unroll
    for (int p = 0; p < 8; p++) gld_lds16(gA[p] + k0, Asb + (p * 512 + t) * 8);
    #pragma unroll
    for (int p = 0; p < 2; p++) gld_lds16(gB[p] + k0, Bsb + (p * 512 + t) * 8);
}

#define MFMA16(ACC, BQ, AQ, IB)                                                   \
    do {                                                                          \
        __builtin_amdgcn_s_setprio(1);                                            \
        _Pragma("unroll")                                                         \
        for (int j_ = 0; j_ < 4; j_++)                                            \
            _Pragma("unroll")                                                     \
            for (int i_ = 0; i_ < 4; i_++)                                        \
                ACC[(IB) + i_][j_] = __builtin_amdgcn_mfma_f32_16x16x32_bf16(     \
                    BQ[j_], AQ[i_], ACC[(IB) + i_][j_], 0, 0, 0);                 \
        __builtin_amdgcn_s_setprio(0);                                            \
        __builtin_amdgcn_sched_barrier(0);                                        \
    } while (0)

__device__ __forceinline__ void compute_step(const bf16* Asb, const bf16* Bsb,
                                             int aB, int bB, f32x4 (&acc)[8][4]) {
    const char* Ab = (const char*)Asb;
    const char* Bb = (const char*)Bsb;
    bf16x8 a0[4], a1[4], b0[4], b1[4];
    __builtin_amdgcn_sched_barrier(0);
    // batch0: A frags 0-3 @ kk0 + B frags 0-3 @ kk0  (8 reads)
    #pragma unroll
    for (int i = 0; i < 4; i++) a0[i] = *(const bf16x8*)(Ab + aB + i * 2048);
    #pragma unroll
    for (int j = 0; j < 4; j++) b0[j] = *(const bf16x8*)(Bb + bB + j * 2048);
    // batch1: A frags 4-7 @ kk0  (4 reads)
    #pragma unroll
    for (int i = 0; i < 4; i++) a1[i] = *(const bf16x8*)(Ab + aB + (i + 4) * 2048);
    asm volatile("s_waitcnt lgkmcnt(4)" ::: "memory");   // batch0 landed
    __builtin_amdgcn_sched_barrier(0);
    MFMA16(acc, b0, a0, 0);
    // batch2: A frags 0-3 @ kk1 + B frags @ kk1  (8 reads)
    #pragma unroll
    for (int i = 0; i < 4; i++) a0[i] = *(const bf16x8*)(Ab + (aB ^ 64) + i * 2048);
    #pragma unroll
    for (int j = 0; j < 4; j++) b1[j] = *(const bf16x8*)(Bb + (bB ^ 64) + j * 2048);
    asm volatile("s_waitcnt lgkmcnt(8)" ::: "memory");   // batch1 landed
    __builtin_amdgcn_sched_barrier(0);
    MFMA16(acc, b0, a1, 4);
    // batch3: A frags 4-7 @ kk1  (4 reads)
    #pragma unroll
    for (int i = 0; i < 4; i++) a1[i] = *(const bf16x8*)(Ab + (aB ^ 64) + (i + 4) * 2048);
    asm volatile("s_waitcnt lgkmcnt(4)" ::: "memory");   // batch2 landed
    __builtin_amdgcn_sched_barrier(0);
    MFMA16(acc, b1, a0, 0);
    asm volatile("s_waitcnt lgkmcnt(0)" ::: "memory");   // batch3 landed
    __builtin_amdgcn_sched_barrier(0);
    MFMA16(acc, b1, a1, 4);
}

template <int EPI>
__global__ __launch_bounds__(512, 1) void gemm_kernel(
    const bf16* __restrict__ A, const bf16* __restrict__ Wt,
    const float* __restrict__ bias, bf16* __restrict__ Cout,
    int Kdim, int Ndim,
    const float* __restrict__ resx,   // EPI_PROJ: x in BCHW f32
    const bf16* __restrict__ resb) {  // EPI_FC2 : x2 token-major bf16
    __shared__ __align__(16) bf16 As[2][512 * 64];   // 2 x 64 KiB
    __shared__ __align__(16) bf16 Bs[2][128 * 64];   // 2 x 16 KiB
    int t = threadIdx.x;

    // n-inner linear order + XCD-chunked bijective remap (m204)
    int nwg = gridDim.x * gridDim.y;
    int bid = blockIdx.y * gridDim.x + blockIdx.x;
    int q8 = nwg >> 3, r8 = nwg & 7, xcd = bid & 7, off = bid >> 3;
    int swz = (xcd < r8 ? xcd * (q8 + 1) : r8 * (q8 + 1) + (xcd - r8) * q8) + off;
    int n0 = (swz % gridDim.x) * 128;
    int m0 = (swz / gridDim.x) * 512;

    int lane = t & 63, wave = t >> 6;          // 8 waves
    int wr = wave >> 1, wc = wave & 1;         // 4M x 2N
    int quad = lane >> 4, lm = lane & 15;
    f32x4 acc[8][4] = {};   // acc[i][j]: m = wr*128+i*16+lm ; n = wc*64+j*16+quad*4+r

    // staging: A 4096 granules (512 rows x 8) -> 8/thread; B 1024 -> 2/thread
    const bf16* gA[8]; const bf16* gB[2];
    #pragma unroll
    for (int p = 0; p < 8; p++) {
        int idx = p * 512 + t;
        int row = idx >> 3, g = idx & 7;
        int gs = g ^ (row & 7);                // inverse swizzle on the SOURCE
        gA[p] = A + (size_t)(m0 + row) * Kdim + gs * 8;
    }
    #pragma unroll
    for (int p = 0; p < 2; p++) {
        int idx = p * 512 + t;
        int row = idx >> 3, g = idx & 7;
        int gs = g ^ (row & 7);
        gB[p] = Wt + (size_t)(n0 + row) * Kdim + gs * 8;
    }

    // LDS byte offsets (kk=0): row*128 + granule*16, granule = quad^(lm&7)
    int g0b = (quad ^ (lm & 7)) * 16;
    int aB = (wr * 128 + lm) * 128 + g0b;      // + i*2048 per m-frag; ^64 for kk1
    int bB = (wc * 64 + lm) * 128 + g0b;       // + j*2048 per n-frag

    int nt = Kdim >> 6;    // 6 (K=384) or 24 (K=1536)
    stage_tile(gA, gB, As[0], Bs[0], t, 0);
    stage_tile(gA, gB, As[1], Bs[1], t, 64);
    asm volatile("s_waitcnt vmcnt(10)" ::: "memory");   // tile0 landed
    SYNC_FENCE();

    for (int tk = 0; tk < nt; ++tk) {
        int par = tk & 1;
        compute_step(As[par], Bs[par], aB, bB, acc);
        if (tk + 1 < nt) {
            SYNC_FENCE();                       // all waves done reading buf[par]
            if (tk + 2 < nt) {
                stage_tile(gA, gB, As[par], Bs[par], t, (tk + 2) << 6);
                asm volatile("s_waitcnt vmcnt(10)" ::: "memory");  // tile tk+1 landed
            } else {
                asm volatile("s_waitcnt vmcnt(0)" ::: "memory");
            }
            SYNC_FENCE();                       // next buffer ready everywhere
        }
    }

    // ---- epilogue: m = m0+wr*128+i*16+lm ; n = n0+wc*64+j*16+quad*4+r
    #pragma unroll
    for (int i = 0; i < 8; i++) {
        int m = m0 + wr * 128 + i * 16 + lm;
        size_t resbase = 0;
        if (EPI == EPI_PROJ) {
            int wi = m / 49, n_ = m % 49;
            int b = wi >> 6, w64 = wi & 63;
            int bh = w64 >> 3, bw = w64 & 7;
            int hs = bh * 7 + n_ / 7 + 3; if (hs >= 56) hs -= 56;
            int wsd = bw * 7 + n_ % 7 + 3; if (wsd >= 56) wsd -= 56;
            resbase = (size_t)b * C_ * 3136 + hs * 56 + wsd;
        }
        #pragma unroll
        for (int j = 0; j < 4; j++) {
            int nb = n0 + wc * 64 + j * 16 + quad * 4;
            f32x4 bj = *(const f32x4*)(bias + nb);
            f32x4 v;
            #pragma unroll
            for (int r = 0; r < 4; r++) v[r] = acc[i][j][r] + bj[r];
            if (EPI == EPI_GELU) {
                #pragma unroll
                for (int r = 0; r < 4; r++) v[r] = fast_gelu(v[r]);
            }
            if (EPI == EPI_PROJ) {
                #pragma unroll
                for (int r = 0; r < 4; r++) v[r] += resx[resbase + (size_t)(nb + r) * 3136];
            }
            if (EPI == EPI_FC2) {
                bf16x4 rb = *(const bf16x4*)(resb + (size_t)m * 384 + nb);
                #pragma unroll
                for (int r = 0; r < 4; r++) v[r] += b2f(rb[r]);
            }
            bf16x4 o;
            #pragma unroll
            for (int r = 0; r < 4; r++) o[r] = f2b(v[r]);
            *(bf16x4*)(Cout + (size_t)m * Ndim + nb) = o;
        }
    }
}

// ---------- K3: MFMA windowed attention. one wave-block per (window, head) ----------
__global__ __launch_bounds__(64) void attn_mfma_kernel(const bf16* __restrict__ qkv,
                                                       bf16* __restrict__ aout) {
    __shared__ __align__(16) bf16 pbuf[64 * 72];
    __shared__ int reg_[64];
    int l = threadIdx.x;
    int wi = blockIdx.x / 12, h = blockIdx.x % 12;
    int i16 = l & 15, quad = l >> 4;

    {
        int tok = l < 49 ? l : 48;
        int w64 = wi & 63;
        int bh = w64 >> 3, bw = w64 & 7;
        int hh = bh * 7 + tok / 7, ww = bw * 7 + tok % 7;
        int fh = hh < 49 ? 0 : (hh < 53 ? 1 : 2);
        int fw = ww < 49 ? 0 : (ww < 53 ? 1 : 2);
        reg_[l] = fh * 3 + fw;
    }
    __syncthreads();

    const bf16* qbase = qkv + (size_t)wi * 49 * 1152 + h * 32;

    f32x4 s_[4][4] = {};
    bf16x8 af[4], bfr[4];
    #pragma unroll
    for (int mi = 0; mi < 4; mi++) {
        int m = mi * 16 + i16; if (m > 48) m = 48;
        af[mi] = *(const bf16x8*)(qbase + (size_t)m * 1152 + quad * 8);
    }
    #pragma unroll
    for (int nt = 0; nt < 4; nt++) {
        int n = nt * 16 + i16; if (n > 48) n = 48;
        bfr[nt] = *(const bf16x8*)(qbase + 384 + (size_t)n * 1152 + quad * 8);
    }
    #pragma unroll
    for (int mi = 0; mi < 4; mi++)
        #pragma unroll
        for (int nt = 0; nt < 4; nt++)
            s_[mi][nt] = __builtin_amdgcn_mfma_f32_16x16x32_bf16(af[mi], bfr[nt], s_[mi][nt], 0, 0, 0);

    int creg[4];
    #pragma unroll
    for (int nt = 0; nt < 4; nt++) {
        int c = nt * 16 + i16; if (c > 48) c = 48;
        creg[nt] = reg_[c];
    }

    const float scale = 0.17677669529663687f;
    #pragma unroll
    for (int mi = 0; mi < 4; mi++) {
        #pragma unroll
        for (int r = 0; r < 4; r++) {
            int row = mi * 16 + quad * 4 + r;
            int rreg = reg_[row];
            float v[4]; float mx = -1e30f;
            #pragma unroll
            for (int nt = 0; nt < 4; nt++) {
                int c = nt * 16 + i16;
                float x = s_[mi][nt][r] * scale;
                if (c > 48) x = -1e30f;
                else if (rreg != creg[nt]) x -= 100.0f;
                v[nt] = x; mx = fmaxf(mx, x);
            }
            #pragma unroll
            for (int m = 8; m; m >>= 1) mx = fmaxf(mx, __shfl_xor(mx, m));
            float sum = 0.f;
            #pragma unroll
            for (int nt = 0; nt < 4; nt++) { v[nt] = __expf(v[nt] - mx); sum += v[nt]; }
            #pragma unroll
            for (int m = 8; m; m >>= 1) sum += __shfl_xor(sum, m);
            float inv = 1.0f / sum;
            #pragma unroll
            for (int nt = 0; nt < 4; nt++)
                pbuf[row * 72 + nt * 16 + i16] = f2b(v[nt] * inv);
        }
    }
    __syncthreads();

    f32x4 o_[4][2] = {};
    const bf16* vbase = qkv + (size_t)wi * 49 * 1152 + 768 + h * 32;
    #pragma unroll
    for (int ks = 0; ks < 2; ks++) {
        bf16x8 pa[4];
        #pragma unroll
        for (int mi = 0; mi < 4; mi++)
            pa[mi] = *(const bf16x8*)(pbuf + (mi * 16 + i16) * 72 + ks * 32 + quad * 8);
        bf16x8 vb[2];
        #pragma unroll
        for (int nt = 0; nt < 2; nt++)
            #pragma unroll
            for (int j = 0; j < 8; j++) {
                int tok = ks * 32 + quad * 8 + j; if (tok > 48) tok = 48;
                vb[nt][j] = vbase[(size_t)tok * 1152 + nt * 16 + i16];
            }
        #pragma unroll
        for (int mi = 0; mi < 4; mi++)
            #pragma unroll
            for (int nt = 0; nt < 2; nt++)
                o_[mi][nt] = __builtin_amdgcn_mfma_f32_16x16x32_bf16(pa[mi], vb[nt], o_[mi][nt], 0, 0, 0);
    }

    bf16* obase = aout + (size_t)wi * 49 * 384 + h * 32;
    #pragma unroll
    for (int mi = 0; mi < 4; mi++)
        #pragma unroll
        for (int r = 0; r < 4; r++) {
            int row = mi * 16 + quad * 4 + r;
            if (row < 49) {
                #pragma unroll
                for (int nt = 0; nt < 2; nt++)
                    obase[(size_t)row * 384 + nt * 16 + i16] = f2b(o_[mi][nt][r]);
            }
        }
}

// ---------- K5: LN2 on token-major bf16 ----------
__global__ __launch_bounds__(256) void ln2_kernel(const bf16* __restrict__ x2,
                                                  const float* __restrict__ g,
                                                  const float* __restrict__ bt,
                                                  bf16* __restrict__ x2n) {
    int wave = threadIdx.x >> 6, lane = threadIdx.x & 63;
    int T = blockIdx.x * 4 + wave;
    const bf16* xp = x2 + (size_t)T * 384;
    float v[6];
    #pragma unroll
    for (int k = 0; k < 6; k++) v[k] = b2f(xp[lane + k * 64]);
    float s = v[0] + v[1] + v[2] + v[3] + v[4] + v[5];
    #pragma unroll
    for (int m = 32; m; m >>= 1) s += __shfl_xor(s, m);
    float mu = s * (1.0f / 384.0f);
    float s2 = 0.f;
    #pragma unroll
    for (int k = 0; k < 6; k++) { float d = v[k] - mu; s2 += d * d; }
    #pragma unroll
    for (int m = 32; m; m >>= 1) s2 += __shfl_xor(s2, m);
    float rstd = rsqrtf(s2 * (1.0f / 384.0f) + 1e-5f);
    bf16* op = x2n + (size_t)T * 384;
    #pragma unroll
    for (int k = 0; k < 6; k++) {
        int c = lane + k * 64;
        op[c] = f2b((v[k] - mu) * rstd * g[c] + bt[c]);
    }
}

// ---------- K8: window reverse + unshift + transpose to BCHW f32 ----------
__global__ __launch_bounds__(256) void untile_kernel(const bf16* __restrict__ otok,
                                                     float* __restrict__ out) {
    __shared__ float tile[56 * 65];
    int t = threadIdx.x;
    int b = blockIdx.x / 336;
    int rem = blockIdx.x % 336;
    int h = rem / 6;
    int c0 = (rem % 6) * 64;
    int hs = h + 53; if (hs >= 56) hs -= 56;
    int bh = hs / 7, th = hs % 7;
    #pragma unroll
    for (int pass = 0; pass < 14; pass++) {
        int w = pass * 4 + (t >> 6);
        int c = t & 63;
        int wsd = w + 53; if (wsd >= 56) wsd -= 56;
        int T = (b * 64 + bh * 8 + wsd / 7) * 49 + th * 7 + wsd % 7;
        tile[w * 65 + c] = b2f(otok[(size_t)T * 384 + c0 + c]);
    }
    __syncthreads();
    #pragma unroll
    for (int pass = 0; pass < 14; pass++) {
        int idx = pass * 256 + t;
        int c = idx / 56, w = idx % 56;
        out[((size_t)(b * 384 + c0 + c)) * 3136 + h * 56 + w] = tile[w * 65 + c];
    }
}

// ---------- launcher ----------
extern "C" void kernel_launch(void* const* d_in, const int* in_sizes, int n_in,
                              void* d_out, int out_size, void* d_ws, size_t ws_size,
                              hipStream_t stream) {
    (void)in_sizes; (void)n_in; (void)out_size; (void)ws_size;
    const float* x      = (const float*)d_in[0];
    const float* n1g    = (const float*)d_in[1];
    const float* n1b    = (const float*)d_in[2];
    const float* qkv_w  = (const float*)d_in[3];
    const float* qkv_b  = (const float*)d_in[4];
    const float* proj_w = (const float*)d_in[5];
    const float* proj_b = (const float*)d_in[6];
    const float* n2g    = (const float*)d_in[7];
    const float* n2b    = (const float*)d_in[8];
    const float* fc1_w  = (const float*)d_in[9];
    const float* fc1_b  = (const float*)d_in[10];
    const float* fc2_w  = (const float*)d_in[11];
    const float* fc2_b  = (const float*)d_in[12];
    float* out = (float*)d_out;
    char* ws = (char*)d_ws;

    bf16* qkv_wT = (bf16*)(ws + 0);          // 884736 B
    bf16* proj_wT = (bf16*)(ws + 884736);    // 294912 B
    bf16* fc1_wT = (bf16*)(ws + 1179648);    // 1179648 B
    bf16* fc2_wT = (bf16*)(ws + 2359296);    // 1179648 B
    bf16* xw   = (bf16*)(ws + 4194304);      // 38535168 B
    bf16* qkvb = (bf16*)(ws + 42729472);     // 115605504 B
    bf16* attn = (bf16*)(ws + 158334976);    // 38535168 B
    bf16* x2   = (bf16*)(ws + 4194304);      // alias xw (dead)
    bf16* x2n  = (bf16*)(ws + 42729472);     // alias qkv (dead)
    bf16* h1   = (bf16*)(ws + 81264640);     // 154140672 B (overlaps dead attn)
    bf16* otok = (bf16*)(ws + 235405312);    // 38535168 B  (peak ws = 274 MB)

    wtrans_kernel<<<(384 * 1152 + 255) / 256, 256, 0, stream>>>(qkv_w, qkv_wT, 384, 1152);
    wtrans_kernel<<<(384 * 384 + 255) / 256, 256, 0, stream>>>(proj_w, proj_wT, 384, 384);
    wtrans_kernel<<<(384 * 1536 + 255) / 256, 256, 0, stream>>>(fc1_w, fc1_wT, 384, 1536);
    wtrans_kernel<<<(1536 * 384 + 255) / 256, 256, 0, stream>>>(fc2_w, fc2_wT, 1536, 384);

    ln1_gather_kernel<<<TOKENS / 4, 256, 0, stream>>>(x, n1g, n1b, xw);

    // grids: x = n-blocks (BN=128), y = m-panels (BM=512, 98 panels)
    gemm_kernel<EPI_NONE><<<dim3(9, 98), 512, 0, stream>>>(
        xw, qkv_wT, qkv_b, qkvb, 384, 1152, nullptr, nullptr);

    attn_mfma_kernel<<<12288, 64, 0, stream>>>(qkvb, attn);

    gemm_kernel<EPI_PROJ><<<dim3(3, 98), 512, 0, stream>>>(
        attn, proj_wT, proj_b, x2, 384, 384, x, nullptr);

    ln2_kernel<<<TOKENS / 4, 256, 0, stream>>>(x2, n2g, n2b, x2n);

    gemm_kernel<EPI_GELU><<<dim3(12, 98), 512, 0, stream>>>(
        x2n, fc1_wT, fc1_b, h1, 384, 1536, nullptr, nullptr);

    gemm_kernel<EPI_FC2><<<dim3(3, 98), 512, 0, stream>>>(
        h1, fc2_wT, fc2_b, otok, 1536, 384, nullptr, x2);

    untile_kernel<<<16 * 336, 256, 0, stream>>>(otok, out);
}